// Round 1
// baseline (500.492 us; speedup 1.0000x reference)
//
#include <hip/hip_runtime.h>

// Problem constants
#define BATCH 32
#define HW    512                    // H == W == 512
#define NPIX  (BATCH * HW * HW)      // 8,388,608 pixels (float4 each)

__device__ __forceinline__ float4 bilinear_sample(const float4* __restrict__ img,
                                                  float px, float py) {
    // img: one batch image, [512][512] of float4 (channels)
    float fx = floorf(px);
    float fy = floorf(py);
    int x0 = (int)fx;
    int y0 = (int)fy;
    int x1 = x0 + 1;
    int y1 = y0 + 1;
    x0 = min(max(x0, 0), HW - 1);
    x1 = min(max(x1, 0), HW - 1);
    y0 = min(max(y0, 0), HW - 1);
    y1 = min(max(y1, 0), HW - 1);
    float x0f = (float)x0, x1f = (float)x1;
    float y0f = (float)y0, y1f = (float)y1;
    // weights use the clipped corner coords but the UNCLIPPED px/py (matches ref)
    float wa = (x1f - px) * (y1f - py);
    float wb = (x1f - px) * (py - y0f);
    float wc = (px - x0f) * (y1f - py);
    float wd = (px - x0f) * (py - y0f);
    float4 Ia = img[y0 * HW + x0];
    float4 Ib = img[y1 * HW + x0];
    float4 Ic = img[y0 * HW + x1];
    float4 Id = img[y1 * HW + x1];
    float4 r;
    r.x = wa * Ia.x + wb * Ib.x + wc * Ic.x + wd * Id.x;
    r.y = wa * Ia.y + wb * Ib.y + wc * Ic.y + wd * Id.y;
    r.z = wa * Ia.z + wb * Ib.z + wc * Ic.z + wd * Id.z;
    r.w = wa * Ia.w + wb * Ib.w + wc * Ic.w + wd * Id.w;
    return r;
}

__global__ __launch_bounds__(256) void stn_kernel(
    const float4* __restrict__ in4,
    const float*  __restrict__ theta1,
    const float*  __restrict__ theta2,
    float4* __restrict__ out0,
    float4* __restrict__ out1,
    float4* __restrict__ out2) {
    int idx = blockIdx.x * 256 + threadIdx.x;
    if (idx >= NPIX) return;
    int j = idx & (HW - 1);          // column
    int i = (idx >> 9) & (HW - 1);   // row
    int b = idx >> 18;               // batch

    // passthrough copy
    float4 v = in4[idx];
    out0[idx] = v;

    // normalized grid coords (linspace(-1,1,512))
    float xg = -1.0f + 2.0f * (float)j * (1.0f / 511.0f);
    float yg = -1.0f + 2.0f * (float)i * (1.0f / 511.0f);

    const float4* imgb = in4 + (size_t)b * (HW * HW);

    // transform 1: scale 0.8 + theta1 translation
    {
        float tx = theta1[2 * b];
        float ty = theta1[2 * b + 1];
        float xs = 0.8f * xg + tx;
        float ys = 0.8f * yg + ty;
        float px = 0.5f * (xs + 1.0f) * 510.0f;   // (max_x - 1) == 510 per ref
        float py = 0.5f * (ys + 1.0f) * 510.0f;
        out1[idx] = bilinear_sample(imgb, px, py);
    }
    // transform 2: scale 0.6 + theta2 translation
    {
        float tx = theta2[2 * b];
        float ty = theta2[2 * b + 1];
        float xs = 0.6f * xg + tx;
        float ys = 0.6f * yg + ty;
        float px = 0.5f * (xs + 1.0f) * 510.0f;
        float py = 0.5f * (ys + 1.0f) * 510.0f;
        out2[idx] = bilinear_sample(imgb, px, py);
    }
}

__global__ void berr_kernel(const float* __restrict__ theta1,
                            const float* __restrict__ theta2,
                            float* __restrict__ out) {
    int k = threadIdx.x;             // 0..127 => (b, c)
    if (k >= BATCH * 4) return;
    int b = k >> 2;
    int c = k & 3;
    float val;
    if (c == 0)      val = fmaxf(0.0f, fabsf(theta1[2 * b])     + 0.8f - 1.0f);
    else if (c == 1) val = fmaxf(0.0f, fabsf(theta1[2 * b + 1]) + 0.8f - 1.0f);
    else if (c == 2) val = fmaxf(0.0f, fabsf(theta2[2 * b])     + 0.6f - 1.0f);
    else             val = fmaxf(0.0f, fabsf(theta2[2 * b + 1]) + 0.6f - 1.0f);
    out[k] = val;
}

extern "C" void kernel_launch(void* const* d_in, const int* in_sizes, int n_in,
                              void* d_out, int out_size, void* d_ws, size_t ws_size,
                              hipStream_t stream) {
    const float4* in4   = (const float4*)d_in[0];
    const float*  th1   = (const float*)d_in[1];
    const float*  th2   = (const float*)d_in[2];
    float* out = (float*)d_out;

    const size_t NF = (size_t)NPIX * 4;       // floats per image tensor
    float4* out0 = (float4*)(out);
    float4* out1 = (float4*)(out + NF);
    float4* out2 = (float4*)(out + 2 * NF);
    float*  berr = out + 3 * NF;

    dim3 block(256);
    dim3 grid(NPIX / 256);
    stn_kernel<<<grid, block, 0, stream>>>(in4, th1, th2, out0, out1, out2);
    berr_kernel<<<1, 128, 0, stream>>>(th1, th2, berr);
}